// Round 3
// baseline (1446.414 us; speedup 1.0000x reference)
//
#include <hip/hip_runtime.h>
#include <cmath>

#define T_STEPS 512
#define BATCH   64
#define ISZ     512
#define HSZ     512

// ---------------------------------------------------------------------------
// Phase 1 (fp32): xw[m][n] = sum_k x[m][k] * w_ih[n][k]   (32768 x 512 x 512)
// fp32 VALU SGEMM (no fp32 MFMA on CDNA4). UNCHANGED from round 2.
// 64x64 tile, BK=32, 256 threads, 4x4 micro-tile per thread.
// ---------------------------------------------------------------------------
__global__ __launch_bounds__(256) void rnn_xw_f32(const float* __restrict__ x,
                                                  const float* __restrict__ wih,
                                                  float* __restrict__ out) {
    __shared__ float As[32][68];
    __shared__ float Bs[32][68];

    const int tid = threadIdx.x;
    const int n0  = blockIdx.x * 64;
    const int m0  = blockIdx.y * 64;
    const int r0  = (tid & 15) * 4;
    const int c0  = (tid >> 4) * 4;
    const int sr  = tid >> 2;
    const int sc  = (tid & 3) * 8;

    float acc[4][4] = {};

    const float* ap = x   + (size_t)(m0 + sr) * ISZ + sc;
    const float* bp = wih + (size_t)(n0 + sr) * ISZ + sc;

    for (int k0 = 0; k0 < ISZ; k0 += 32) {
        const float4 a0 = *(const float4*)(ap + k0);
        const float4 a1 = *(const float4*)(ap + k0 + 4);
        const float4 b0 = *(const float4*)(bp + k0);
        const float4 b1 = *(const float4*)(bp + k0 + 4);
        __syncthreads();
        As[sc + 0][sr] = a0.x; As[sc + 1][sr] = a0.y;
        As[sc + 2][sr] = a0.z; As[sc + 3][sr] = a0.w;
        As[sc + 4][sr] = a1.x; As[sc + 5][sr] = a1.y;
        As[sc + 6][sr] = a1.z; As[sc + 7][sr] = a1.w;
        Bs[sc + 0][sr] = b0.x; Bs[sc + 1][sr] = b0.y;
        Bs[sc + 2][sr] = b0.z; Bs[sc + 3][sr] = b0.w;
        Bs[sc + 4][sr] = b1.x; Bs[sc + 5][sr] = b1.y;
        Bs[sc + 6][sr] = b1.z; Bs[sc + 7][sr] = b1.w;
        __syncthreads();

        #pragma unroll
        for (int k = 0; k < 32; ++k) {
            const float4 av = *(const float4*)&As[k][r0];
            const float4 bv = *(const float4*)&Bs[k][c0];
            const float a[4] = {av.x, av.y, av.z, av.w};
            const float b[4] = {bv.x, bv.y, bv.z, bv.w};
            #pragma unroll
            for (int i = 0; i < 4; ++i)
                #pragma unroll
                for (int j = 0; j < 4; ++j)
                    acc[i][j] = fmaf(a[i], b[j], acc[i][j]);
        }
    }

    #pragma unroll
    for (int i = 0; i < 4; ++i) {
        float4 v; v.x = acc[i][0]; v.y = acc[i][1]; v.z = acc[i][2]; v.w = acc[i][3];
        *(float4*)(out + (size_t)(m0 + r0 + i) * HSZ + n0 + c0) = v;
    }
}

// ---------------------------------------------------------------------------
// Per-element tagged exchange: one atomic u64 = {tag = t+1 (hi32), h bits
// (lo32)}. Value+tag in the SAME word => only per-location atomicity of an
// aligned 8B agent-scope access is required. No flags, no release/acquire,
// no cross-location ordering. Depth-2 ring: a WG reaches step t only after
// seeing every peer's tag-t words, proving peers finished step t-1 and have
// consumed the h[t-2] this store overwrites.
// ---------------------------------------------------------------------------
__device__ __forceinline__ void ex_store(unsigned long long* w, float h, unsigned tag) {
    union { float f; unsigned u; } c; c.f = h;
    const unsigned long long v = ((unsigned long long)tag << 32) | (unsigned long long)c.u;
    __hip_atomic_store(w, v, __ATOMIC_RELAXED, __HIP_MEMORY_SCOPE_AGENT);
}

__device__ __forceinline__ float ex_wait(const unsigned long long* w, unsigned tag) {
    unsigned long long v;
    for (;;) {
        v = __hip_atomic_load(w, __ATOMIC_RELAXED, __HIP_MEMORY_SCOPE_AGENT);
        if ((unsigned)(v >> 32) == tag) break;
        __builtin_amdgcn_s_sleep(1);
    }
    union { unsigned u; float f; } c; c.u = (unsigned)v;
    return c.f;
}

// ---------------------------------------------------------------------------
// Phase 2: sequential recurrence. 256 WGs (32 batch-pairs x 8 neuron-slices),
// 136 KB LDS => 1 WG/CU => all 256 co-resident (rounds 1-2 did not hang,
// confirming co-residency). W_hh slice (64 rows x 512 k, fp32) in LDS.
// h exchange via tagged words in d_ws; d_out written with plain stores only.
// ---------------------------------------------------------------------------
__global__ __launch_bounds__(512) void rnn_rec(const float* __restrict__ whh,
                                               float* __restrict__ out,
                                               unsigned long long* __restrict__ ex) {
    extern __shared__ char smem[];
    float4* w4  = (float4*)smem;                       // [128][64] float4 = 128 KB
    float*  hl  = (float*)(smem + 131072);             // [2][512] fp32 = 4 KB
    float4* hl4 = (float4*)hl;
    float*  red = (float*)(smem + 131072 + 4096);      // [2][8][64] fp32 = 4 KB

    const int tid = threadIdx.x;
    const int p   = blockIdx.x >> 3;   // batch pair 0..31
    const int g   = blockIdx.x & 7;    // neuron slice 0..7
    const int j0  = g * 64;
    const int j   = tid & 63;
    const int o   = tid >> 6;          // k-octant 0..7

    // stage weight slice: w4[k>>2][j] = whh[j0+j][k..k+3]
    {
        const float* wr = whh + (size_t)(j0 + j) * HSZ + o * 64;
        #pragma unroll
        for (int i = 0; i < 16; ++i)
            w4[(o * 16 + i) * 64 + j] = *(const float4*)(wr + 4 * i);
    }
    __syncthreads();

    const int bsel = tid >> 6;   // valid for tid<128: 0/1
    const int jj   = tid & 63;

    for (int t = 0; t < T_STEPS; ++t) {
        // prefetch own xw slice (phase-1 output; only this thread ever
        // overwrites this address, at the bottom of this iteration)
        float xwv = 0.f;
        if (tid < 128)
            xwv = out[((size_t)t * BATCH + 2 * p + bsel) * HSZ + j0 + jj];

        float acc = 0.f;
        if (t > 0) {
            const int s = (t - 1) & 1;
            // stage h[t-1] (2 batches x 512) from tagged exchange words
            #pragma unroll
            for (int e0 = 0; e0 < 2; ++e0) {
                const int e   = tid + e0 * 512;   // 0..1023
                const int b   = e >> 9;           // 0/1
                const int idx = e & 511;
                hl[e] = ex_wait(&ex[(size_t)s * 32768 + (size_t)(2 * p + b) * 512 + idx],
                                (unsigned)t);
            }
            __syncthreads();                                      // B2
            float a0 = 0.f, a1 = 0.f;
            #pragma unroll
            for (int i = 0; i < 16; ++i) {
                const int k4 = o * 16 + i;
                const float4 wv = w4[k4 * 64 + j];
                const float4 h0 = hl4[k4];
                const float4 h1 = hl4[128 + k4];
                a0 += wv.x * h0.x; a0 += wv.y * h0.y; a0 += wv.z * h0.z; a0 += wv.w * h0.w;
                a1 += wv.x * h1.x; a1 += wv.y * h1.y; a1 += wv.z * h1.z; a1 += wv.w * h1.w;
            }
            red[o * 64 + j]       = a0;
            red[512 + o * 64 + j] = a1;
            __syncthreads();                                      // B3
            if (tid < 128) {
                #pragma unroll
                for (int oo = 0; oo < 8; ++oo)
                    acc += red[bsel * 512 + oo * 64 + jj];
            }
        }

        if (tid < 128) {
            const float hv = tanhf(acc + xwv);
            out[((size_t)t * BATCH + 2 * p + bsel) * HSZ + j0 + jj] = hv;
            if (t < T_STEPS - 1)
                ex_store(&ex[(size_t)(t & 1) * 32768 + (size_t)(2 * p + bsel) * 512 + j0 + jj],
                         hv, (unsigned)(t + 1));
            else
                out[(size_t)T_STEPS * BATCH * HSZ + (size_t)(2 * p + bsel) * HSZ + j0 + jj] = hv;
        }
        __syncthreads();                                          // B4
    }
}

// ---------------------------------------------------------------------------
extern "C" void kernel_launch(void* const* d_in, const int* in_sizes, int n_in,
                              void* d_out, int out_size, void* d_ws, size_t ws_size,
                              hipStream_t stream) {
    (void)in_sizes; (void)n_in; (void)out_size; (void)ws_size;
    const float* x    = (const float*)d_in[0];   // (512,64,512)
    const float* wih  = (const float*)d_in[1];   // (512,512)
    const float* whh  = (const float*)d_in[2];   // (512,512)
    float*       out  = (float*)d_out;           // h_all (T,B,H) ++ h_last (B,H)
    unsigned long long* ex = (unsigned long long*)d_ws;   // 2*64*512 u64 = 512 KB

    // opt-in to >64 KB dynamic LDS for phase 2 (idempotent, capture-safe)
    (void)hipFuncSetAttribute((const void*)rnn_rec,
                              hipFuncAttributeMaxDynamicSharedMemorySize, 160 * 1024);

    // zero the exchange region: tag 0 matches no step (tags are 1..511)
    (void)hipMemsetAsync(d_ws, 0, 2 * 64 * 512 * sizeof(unsigned long long), stream);

    hipLaunchKernelGGL(rnn_xw_f32, dim3(8, 512), dim3(256), 0, stream, x, wih, out);
    hipLaunchKernelGGL(rnn_rec, dim3(256), dim3(512), 139264, stream, whh, out, ex);
}

// Round 4
// 1140.309 us; speedup vs baseline: 1.2684x; 1.2684x over previous
//
#include <hip/hip_runtime.h>
#include <cmath>

#define T_STEPS 512
#define BATCH   64
#define ISZ     512
#define HSZ     512
#define EXN     32768   // u64 words per ring slot (64 batches x 512)

// ---------------------------------------------------------------------------
// Phase 1 (fp32): xw[m][n] = sum_k x[m][k] * w_ih[n][k]   (32768 x 512 x 512)
// fp32 VALU SGEMM (no fp32 MFMA on CDNA4). UNCHANGED from round 3 (proven).
// ---------------------------------------------------------------------------
__global__ __launch_bounds__(256) void rnn_xw_f32(const float* __restrict__ x,
                                                  const float* __restrict__ wih,
                                                  float* __restrict__ out) {
    __shared__ float As[32][68];
    __shared__ float Bs[32][68];

    const int tid = threadIdx.x;
    const int n0  = blockIdx.x * 64;
    const int m0  = blockIdx.y * 64;
    const int r0  = (tid & 15) * 4;
    const int c0  = (tid >> 4) * 4;
    const int sr  = tid >> 2;
    const int sc  = (tid & 3) * 8;

    float acc[4][4] = {};

    const float* ap = x   + (size_t)(m0 + sr) * ISZ + sc;
    const float* bp = wih + (size_t)(n0 + sr) * ISZ + sc;

    for (int k0 = 0; k0 < ISZ; k0 += 32) {
        const float4 a0 = *(const float4*)(ap + k0);
        const float4 a1 = *(const float4*)(ap + k0 + 4);
        const float4 b0 = *(const float4*)(bp + k0);
        const float4 b1 = *(const float4*)(bp + k0 + 4);
        __syncthreads();
        As[sc + 0][sr] = a0.x; As[sc + 1][sr] = a0.y;
        As[sc + 2][sr] = a0.z; As[sc + 3][sr] = a0.w;
        As[sc + 4][sr] = a1.x; As[sc + 5][sr] = a1.y;
        As[sc + 6][sr] = a1.z; As[sc + 7][sr] = a1.w;
        Bs[sc + 0][sr] = b0.x; Bs[sc + 1][sr] = b0.y;
        Bs[sc + 2][sr] = b0.z; Bs[sc + 3][sr] = b0.w;
        Bs[sc + 4][sr] = b1.x; Bs[sc + 5][sr] = b1.y;
        Bs[sc + 6][sr] = b1.z; Bs[sc + 7][sr] = b1.w;
        __syncthreads();

        #pragma unroll
        for (int k = 0; k < 32; ++k) {
            const float4 av = *(const float4*)&As[k][r0];
            const float4 bv = *(const float4*)&Bs[k][c0];
            const float a[4] = {av.x, av.y, av.z, av.w};
            const float b[4] = {bv.x, bv.y, bv.z, bv.w};
            #pragma unroll
            for (int i = 0; i < 4; ++i)
                #pragma unroll
                for (int j = 0; j < 4; ++j)
                    acc[i][j] = fmaf(a[i], b[j], acc[i][j]);
        }
    }

    #pragma unroll
    for (int i = 0; i < 4; ++i) {
        float4 v; v.x = acc[i][0]; v.y = acc[i][1]; v.z = acc[i][2]; v.w = acc[i][3];
        *(float4*)(out + (size_t)(m0 + r0 + i) * HSZ + n0 + c0) = v;
    }
}

// ---------------------------------------------------------------------------
// Tagged-word exchange (unchanged protocol, proven round 3): one atomic u64 =
// {tag = t+1 (hi32), h bits (lo32)}. Per-location atomicity only; safety of
// the depth-2 ring follows from data dependency (stored h depends on all
// loaded h of its batch) + poll-all-words before advancing.
// ---------------------------------------------------------------------------
__device__ __forceinline__ void ex_store(unsigned long long* w, float h, unsigned tag) {
    union { float f; unsigned u; } c; c.f = h;
    const unsigned long long v = ((unsigned long long)tag << 32) | (unsigned long long)c.u;
    __hip_atomic_store(w, v, __ATOMIC_RELAXED, __HIP_MEMORY_SCOPE_AGENT);
}

// ---------------------------------------------------------------------------
// Phase 2: sequential recurrence. 256 WGs (32 batch-pairs x 8 neuron-slices).
// __launch_bounds__(512,2) => up to 256 VGPR/thread and 1 WG/CU (VGPR-limited)
// => all 256 WGs co-resident (empirically confirmed rounds 1-3: no hang).
// W_hh slice lives in REGISTERS (128 VGPR/thread, time-invariant -> zero LDS
// traffic for weights). Per-thread micro-tile: 4 outputs x 32 k x 1 batch.
// LDS per step: 8 broadcast b128 h-reads/thread + tiny reduction.
// ---------------------------------------------------------------------------
__global__ __launch_bounds__(512, 2) void rnn_rec(const float* __restrict__ whh,
                                                  float* __restrict__ out,
                                                  unsigned long long* __restrict__ ex) {
    __shared__ float hl[1024];            // [2 batches][512] h(t-1)
    __shared__ float red[1024];           // [8 kseg-pairs][32 (jg,b)][4 j]
    float4* hl4 = (float4*)hl;

    const int tid  = threadIdx.x;
    const int p    = blockIdx.x >> 3;     // batch pair 0..31
    const int g    = blockIdx.x & 7;      // neuron slice 0..7
    const int j0   = g * 64;
    const int b    = tid & 1;             // batch within pair
    const int jg   = (tid >> 1) & 15;     // output group (4 j each)
    const int kseg = tid >> 5;            // k segment 0..15 (32 k each)
    const int lane = tid & 63;
    const int wv   = tid >> 6;            // wave id 0..7 (kseg pair)

    // ---- W_hh micro-panel into registers: rows j0+jg*4+jx, cols kseg*32.. ----
    float4 w[4][8];
    #pragma unroll
    for (int jx = 0; jx < 4; ++jx) {
        const float* wr = whh + (size_t)(j0 + jg * 4 + jx) * HSZ + kseg * 32;
        #pragma unroll
        for (int i = 0; i < 8; ++i)
            w[jx][i] = *(const float4*)(wr + 4 * i);
    }

    // final-output role (threads 0..127): fb = batch, fj = output within slice
    const int fb = tid & 1;
    const int fj = (tid >> 1) & 63;

    unsigned long long* exw0 = ex + (size_t)(2 * p + 0) * 512 + tid;
    unsigned long long* exw1 = ex + (size_t)(2 * p + 1) * 512 + tid;

    for (int t = 0; t < T_STEPS; ++t) {
        // prefetch own xw (phase-1 output; same thread overwrites it below)
        float xwv = 0.f;
        if (tid < 128)
            xwv = out[((size_t)t * BATCH + 2 * p + fb) * HSZ + j0 + fj];

        float acc = 0.f;
        if (t > 0) {
            const size_t soff = (size_t)((t - 1) & 1) * EXN;
            // both exchange words in flight together: one round trip
            unsigned long long v0 = __hip_atomic_load(exw0 + soff, __ATOMIC_RELAXED,
                                                      __HIP_MEMORY_SCOPE_AGENT);
            unsigned long long v1 = __hip_atomic_load(exw1 + soff, __ATOMIC_RELAXED,
                                                      __HIP_MEMORY_SCOPE_AGENT);
            while ((unsigned)(v0 >> 32) != (unsigned)t ||
                   (unsigned)(v1 >> 32) != (unsigned)t) {
                __builtin_amdgcn_s_sleep(1);
                v0 = __hip_atomic_load(exw0 + soff, __ATOMIC_RELAXED,
                                       __HIP_MEMORY_SCOPE_AGENT);
                v1 = __hip_atomic_load(exw1 + soff, __ATOMIC_RELAXED,
                                       __HIP_MEMORY_SCOPE_AGENT);
            }
            union { unsigned u; float f; } c0, c1;
            c0.u = (unsigned)v0; c1.u = (unsigned)v1;
            hl[tid]       = c0.f;   // batch 0
            hl[512 + tid] = c1.f;   // batch 1
            __syncthreads();                                      // B1

            // dot: 4 outputs x 32 k, weights in regs, h via broadcast b128
            float p4[4] = {0.f, 0.f, 0.f, 0.f};
            #pragma unroll
            for (int i = 0; i < 8; ++i) {
                const float4 h4 = hl4[b * 128 + kseg * 8 + i];
                #pragma unroll
                for (int jx = 0; jx < 4; ++jx) {
                    p4[jx] = fmaf(w[jx][i].x, h4.x, p4[jx]);
                    p4[jx] = fmaf(w[jx][i].y, h4.y, p4[jx]);
                    p4[jx] = fmaf(w[jx][i].z, h4.z, p4[jx]);
                    p4[jx] = fmaf(w[jx][i].w, h4.w, p4[jx]);
                }
            }
            // fold kseg pair (lane ^ 32), then park 8 wave-partials in LDS
            #pragma unroll
            for (int jx = 0; jx < 4; ++jx)
                p4[jx] += __shfl_xor(p4[jx], 32, 64);
            if (lane < 32) {
                float4 v; v.x = p4[0]; v.y = p4[1]; v.z = p4[2]; v.w = p4[3];
                *(float4*)&red[(wv * 32 + lane) * 4] = v;   // lane = jg*2+b
            }
            __syncthreads();                                      // B2
            if (tid < 128) {
                const int c = (fj >> 2) * 2 + fb;
                const int ji = fj & 3;
                #pragma unroll
                for (int w8 = 0; w8 < 8; ++w8)
                    acc += red[(w8 * 32 + c) * 4 + ji];
            }
        }

        if (tid < 128) {
            const float a2 = acc + xwv;
            const float e  = __expf(2.f * a2);           // tanh = (e-1)/(e+1)
            const float hv = 1.f - 2.f / (e + 1.f);
            out[((size_t)t * BATCH + 2 * p + fb) * HSZ + j0 + fj] = hv;
            if (t < T_STEPS - 1)
                ex_store(ex + (size_t)(t & 1) * EXN + (size_t)(2 * p + fb) * 512 + j0 + fj,
                         hv, (unsigned)(t + 1));
            else
                out[(size_t)T_STEPS * BATCH * HSZ + (size_t)(2 * p + fb) * HSZ + j0 + fj] = hv;
        }
        // no trailing barrier: B1(t+1)/B2(t+1) arrival ordering makes
        // hl/red reuse safe; ex_store drain overlaps next step's poll.
    }
}

// ---------------------------------------------------------------------------
extern "C" void kernel_launch(void* const* d_in, const int* in_sizes, int n_in,
                              void* d_out, int out_size, void* d_ws, size_t ws_size,
                              hipStream_t stream) {
    (void)in_sizes; (void)n_in; (void)out_size; (void)ws_size;
    const float* x    = (const float*)d_in[0];   // (512,64,512)
    const float* wih  = (const float*)d_in[1];   // (512,512)
    const float* whh  = (const float*)d_in[2];   // (512,512)
    float*       out  = (float*)d_out;           // h_all (T,B,H) ++ h_last (B,H)
    unsigned long long* ex = (unsigned long long*)d_ws;   // 2*EXN u64 = 512 KB

    // zero the exchange region: harness poisons d_ws with 0xAA each launch,
    // and stale tags from a previous launch would alias -> must re-zero.
    (void)hipMemsetAsync(d_ws, 0, 2 * EXN * sizeof(unsigned long long), stream);

    hipLaunchKernelGGL(rnn_xw_f32, dim3(8, 512), dim3(256), 0, stream, x, wih, out);
    hipLaunchKernelGGL(rnn_rec, dim3(256), dim3(512), 0, stream, whh, out, ex);
}